// Round 1
// baseline (644.468 us; speedup 1.0000x reference)
//
#include <hip/hip_runtime.h>

typedef float floatx4 __attribute__((ext_vector_type(4)));

#define GEMM_M 8192   // A*B = 4*2048
#define GEMM_N 8192   // OUT
#define GEMM_K 2048   // C

// ---------------------------------------------------------------------------
// Quantize fp32 -> fp8 e4m3fn (OCP), scale applied before cast (RNE in HW).
// Each thread: 16 floats -> 16 bytes. n16 = total_elems/16 threads launched.
// ---------------------------------------------------------------------------
__global__ __launch_bounds__(256) void quant_e4m3(const float* __restrict__ x,
                                                  const float* __restrict__ scale,
                                                  int4* __restrict__ q)
{
    const int i = blockIdx.x * blockDim.x + threadIdx.x;
    const float s = scale[0];
    const float4* __restrict__ x4 = (const float4*)x;
    float4 v0 = x4[i * 4 + 0];
    float4 v1 = x4[i * 4 + 1];
    float4 v2 = x4[i * 4 + 2];
    float4 v3 = x4[i * 4 + 3];
    int4 r;
    int p;
    p = __builtin_amdgcn_cvt_pk_fp8_f32(v0.x * s, v0.y * s, 0, false);
    p = __builtin_amdgcn_cvt_pk_fp8_f32(v0.z * s, v0.w * s, p, true);
    r.x = p;
    p = __builtin_amdgcn_cvt_pk_fp8_f32(v1.x * s, v1.y * s, 0, false);
    p = __builtin_amdgcn_cvt_pk_fp8_f32(v1.z * s, v1.w * s, p, true);
    r.y = p;
    p = __builtin_amdgcn_cvt_pk_fp8_f32(v2.x * s, v2.y * s, 0, false);
    p = __builtin_amdgcn_cvt_pk_fp8_f32(v2.z * s, v2.w * s, p, true);
    r.z = p;
    p = __builtin_amdgcn_cvt_pk_fp8_f32(v3.x * s, v3.y * s, 0, false);
    p = __builtin_amdgcn_cvt_pk_fp8_f32(v3.z * s, v3.w * s, p, true);
    r.w = p;
    q[i] = r;
}

// ---------------------------------------------------------------------------
// TN fp8 GEMM: C[M,N] = Aq[M,K] * Bq[N,K]^T, dequant by 1/(sa*sb) at the end.
// 128x128 block tile, BK=64, 256 threads (4 waves, 2x2), wave tile 64x64 as
// 4x4 grid of 16x16 mfma_f32_16x16x32_fp8_fp8.
//
// LDS staged via global_load_lds width=16 (flat layout required). 16B chunks
// are XOR-swizzled on the GLOBAL side: LDS chunk (r, c) holds global chunk
// (r, c ^ (r&3)), making the b64 fragment reads bank-balanced (4/bank).
// ---------------------------------------------------------------------------
__global__ __launch_bounds__(256) void gemm_fp8_tn(
    const unsigned char* __restrict__ Aq,   // [M,K] fp8
    const unsigned char* __restrict__ Bq,   // [N,K] fp8
    float* __restrict__ C,                  // [M,N]
    const float* __restrict__ sa,
    const float* __restrict__ sb)
{
    __shared__ __align__(16) unsigned char sA[128 * 64];
    __shared__ __align__(16) unsigned char sB[128 * 64];

    const int tid  = threadIdx.x;
    const int lane = tid & 63;
    const int wave = tid >> 6;
    const int bn   = blockIdx.x;   // N block
    const int bm   = blockIdx.y;   // M block

    // ---- staging: 8 segs of 1024B per tile; wave w does segs {2w, 2w+1} ----
    // seg s, lane l -> LDS offset s*1024 + l*16 ; tile row r = s*16 + (l>>2)
    // global chunk col = (l&3) ^ (r&3)   (the swizzle, r&3 == (l>>2)&3)
    const int rA0  = (wave * 2 + 0) * 16 + (lane >> 2);
    const int rA1  = (wave * 2 + 1) * 16 + (lane >> 2);
    const int cswz = (((lane & 3) ^ ((lane >> 2) & 3)) << 4);  // byte offset in row

    const unsigned char* gA0 = Aq + (size_t)(bm * 128 + rA0) * GEMM_K + cswz;
    const unsigned char* gA1 = Aq + (size_t)(bm * 128 + rA1) * GEMM_K + cswz;
    const unsigned char* gB0 = Bq + (size_t)(bn * 128 + rA0) * GEMM_K + cswz;
    const unsigned char* gB1 = Bq + (size_t)(bn * 128 + rA1) * GEMM_K + cswz;

    unsigned char* lA0 = &sA[(wave * 2 + 0) * 1024 + lane * 16];
    unsigned char* lA1 = &sA[(wave * 2 + 1) * 1024 + lane * 16];
    unsigned char* lB0 = &sB[(wave * 2 + 0) * 1024 + lane * 16];
    unsigned char* lB1 = &sB[(wave * 2 + 1) * 1024 + lane * 16];

    // ---- fragment addresses ----
    // A frag: lane holds A[m = lane&15][k = 8*(lane>>4) + j], j=0..7  (b64)
    // stored chunk = (k>>4) ^ (m&3); within-chunk = k&15
    const int mloc = lane & 15;
    const int g    = lane >> 4;
    const int chunkoff = ((((g >> 1) ^ (mloc & 3)) << 4) | ((g & 1) << 3));
    const int wm = wave >> 1, wn = wave & 1;

    unsigned aoff[4], boff[4];
#pragma unroll
    for (int t = 0; t < 4; ++t) {
        aoff[t] = (unsigned)((wm * 64 + t * 16 + mloc) << 6) + chunkoff;
        boff[t] = (unsigned)((wn * 64 + t * 16 + mloc) << 6) + chunkoff;
    }

    floatx4 acc[4][4];
#pragma unroll
    for (int i = 0; i < 4; ++i)
#pragma unroll
        for (int j = 0; j < 4; ++j)
            acc[i][j] = (floatx4){0.f, 0.f, 0.f, 0.f};

    for (int kt = 0; kt < GEMM_K / 64; ++kt) {
        const int kb = kt * 64;
        __builtin_amdgcn_global_load_lds(
            (const __attribute__((address_space(1))) void*)(gA0 + kb),
            (__attribute__((address_space(3))) void*)lA0, 16, 0, 0);
        __builtin_amdgcn_global_load_lds(
            (const __attribute__((address_space(1))) void*)(gA1 + kb),
            (__attribute__((address_space(3))) void*)lA1, 16, 0, 0);
        __builtin_amdgcn_global_load_lds(
            (const __attribute__((address_space(1))) void*)(gB0 + kb),
            (__attribute__((address_space(3))) void*)lB0, 16, 0, 0);
        __builtin_amdgcn_global_load_lds(
            (const __attribute__((address_space(1))) void*)(gB1 + kb),
            (__attribute__((address_space(3))) void*)lB1, 16, 0, 0);
        __syncthreads();

        long a[4], b[4];
        // k-step 0 (k = 0..31 of this tile)
#pragma unroll
        for (int t = 0; t < 4; ++t) a[t] = *(const long*)&sA[aoff[t]];
#pragma unroll
        for (int t = 0; t < 4; ++t) b[t] = *(const long*)&sB[boff[t]];
#pragma unroll
        for (int i = 0; i < 4; ++i)
#pragma unroll
            for (int j = 0; j < 4; ++j)
                acc[i][j] = __builtin_amdgcn_mfma_f32_16x16x32_fp8_fp8(
                    a[i], b[j], acc[i][j], 0, 0, 0);

        // k-step 1 (k = 32..63): stored chunk flips bit 1 -> addr ^ 32
#pragma unroll
        for (int t = 0; t < 4; ++t) a[t] = *(const long*)&sA[aoff[t] ^ 32u];
#pragma unroll
        for (int t = 0; t < 4; ++t) b[t] = *(const long*)&sB[boff[t] ^ 32u];
#pragma unroll
        for (int i = 0; i < 4; ++i)
#pragma unroll
            for (int j = 0; j < 4; ++j)
                acc[i][j] = __builtin_amdgcn_mfma_f32_16x16x32_fp8_fp8(
                    a[i], b[j], acc[i][j], 0, 0, 0);

        __syncthreads();
    }

    // ---- epilogue: dequant + store. D[m][n]: m = 4*(lane>>4)+reg, n = lane&15
    const float inv = 1.0f / (sa[0] * sb[0]);
    const int row0 = bm * 128 + wm * 64 + g * 4;
    const int col0 = bn * 128 + wn * 64 + mloc;
#pragma unroll
    for (int ti = 0; ti < 4; ++ti)
#pragma unroll
        for (int tj = 0; tj < 4; ++tj)
#pragma unroll
            for (int r = 0; r < 4; ++r)
                C[(size_t)(row0 + ti * 16 + r) * GEMM_N + (col0 + tj * 16)] =
                    acc[ti][tj][r] * inv;
}

extern "C" void kernel_launch(void* const* d_in, const int* in_sizes, int n_in,
                              void* d_out, int out_size, void* d_ws, size_t ws_size,
                              hipStream_t stream) {
    const float* x    = (const float*)d_in[0];   // [4,2048,2048]
    const float* w    = (const float*)d_in[1];   // [8192,2048]
    const float* s_in = (const float*)d_in[2];   // input_scale_e4m3
    const float* s_w  = (const float*)d_in[3];   // weight_scale_e4m3
    float* out = (float*)d_out;                  // [4,2048,8192] fp32

    unsigned char* qx = (unsigned char*)d_ws;                       // 16 MB
    unsigned char* qw = qx + (size_t)GEMM_M * GEMM_K;               // 16 MB

    // 16 elems/thread
    const int nthr_x = in_sizes[0] / 16;   // 1,048,576
    const int nthr_w = in_sizes[1] / 16;   // 1,048,576
    quant_e4m3<<<nthr_x / 256, 256, 0, stream>>>(x, s_in, (int4*)qx);
    quant_e4m3<<<nthr_w / 256, 256, 0, stream>>>(w, s_w, (int4*)qw);

    dim3 grid(GEMM_N / 128, GEMM_M / 128);   // (64, 64)
    gemm_fp8_tn<<<grid, 256, 0, stream>>>(qx, qw, out, s_in, s_w);
}

// Round 2
// 484.998 us; speedup vs baseline: 1.3288x; 1.3288x over previous
//
#include <hip/hip_runtime.h>

typedef float floatx16 __attribute__((ext_vector_type(16)));
typedef int   intx4    __attribute__((ext_vector_type(4)));
typedef int   intx8    __attribute__((ext_vector_type(8)));

#define GEMM_M 8192   // A*B = 4*2048
#define GEMM_N 8192   // OUT
#define GEMM_K 2048   // C

// ---------------------------------------------------------------------------
// Quantize fp32 -> fp8 e4m3fn (OCP), scale applied before cast (RNE in HW).
// Each thread: 16 floats -> 16 bytes.
// ---------------------------------------------------------------------------
__global__ __launch_bounds__(256) void quant_e4m3(const float* __restrict__ x,
                                                  const float* __restrict__ scale,
                                                  int4* __restrict__ q)
{
    const int i = blockIdx.x * blockDim.x + threadIdx.x;
    const float s = scale[0];
    const float4* __restrict__ x4 = (const float4*)x;
    float4 v0 = x4[i * 4 + 0];
    float4 v1 = x4[i * 4 + 1];
    float4 v2 = x4[i * 4 + 2];
    float4 v3 = x4[i * 4 + 3];
    int4 r;
    int p;
    p = __builtin_amdgcn_cvt_pk_fp8_f32(v0.x * s, v0.y * s, 0, false);
    p = __builtin_amdgcn_cvt_pk_fp8_f32(v0.z * s, v0.w * s, p, true);
    r.x = p;
    p = __builtin_amdgcn_cvt_pk_fp8_f32(v1.x * s, v1.y * s, 0, false);
    p = __builtin_amdgcn_cvt_pk_fp8_f32(v1.z * s, v1.w * s, p, true);
    r.y = p;
    p = __builtin_amdgcn_cvt_pk_fp8_f32(v2.x * s, v2.y * s, 0, false);
    p = __builtin_amdgcn_cvt_pk_fp8_f32(v2.z * s, v2.w * s, p, true);
    r.z = p;
    p = __builtin_amdgcn_cvt_pk_fp8_f32(v3.x * s, v3.y * s, 0, false);
    p = __builtin_amdgcn_cvt_pk_fp8_f32(v3.z * s, v3.w * s, p, true);
    r.w = p;
    q[i] = r;
}

// ---------------------------------------------------------------------------
// TN fp8 GEMM via MX-scaled MFMA at unit scale (0x7f -> 2^0 = 1.0):
//   mfma_scale_f32_32x32x64_f8f6f4, cbsz=blgp=0 (fp8 e4m3 both operands).
// 128x128 block tile, BK=64 (= one MFMA K-step), 256 threads (4 waves, 2x2),
// wave tile 64x64 as 2x2 of 32x32 tiles.
//
// LDS staged flat via global_load_lds width=16. 16B chunks XOR-swizzled on
// the GLOBAL side with s(r) = (r>>1)&3: LDS chunk c of row r holds global
// chunk c ^ s(r). Fragment b128 reads then hit all 32 banks exactly 4x per
// half-wave phase (the b128 minimum) instead of 4-way conflicts.
//
// A-frag (32x32x64): lane holds A[m=lane&31][k=32*(lane>>5)+j], j=0..31,
// i.e. global chunks {2h, 2h+1} of its row (h=lane>>5). B symmetric (B is
// [N,K] row-major => K-major like A).
// C/D: col=lane&31, row=(reg&3)+8*(reg>>2)+4*(lane>>5)  [m74/m101]
// ---------------------------------------------------------------------------
__global__ __launch_bounds__(256) void gemm_fp8_mx(
    const unsigned char* __restrict__ Aq,   // [M,K] fp8
    const unsigned char* __restrict__ Bq,   // [N,K] fp8
    float* __restrict__ C,                  // [M,N]
    const float* __restrict__ sa,
    const float* __restrict__ sb)
{
    __shared__ __align__(16) unsigned char sA[128 * 64];
    __shared__ __align__(16) unsigned char sB[128 * 64];

    const int tid  = threadIdx.x;
    const int lane = tid & 63;
    const int wave = tid >> 6;
    const int bn   = blockIdx.x;   // N block
    const int bm   = blockIdx.y;   // M block

    // ---- staging: 8 segs of 1024B per tile; wave w does segs {2w, 2w+1} ----
    // seg s, lane l -> LDS offset s*1024 + l*16 ; tile row r = s*16 + (l>>2)
    // global chunk = (l&3) ^ ((r>>1)&3) = (l&3) ^ ((l>>3)&3)
    const int r0   = (wave * 2 + 0) * 16 + (lane >> 2);
    const int r1   = (wave * 2 + 1) * 16 + (lane >> 2);
    const int cswz = (((lane & 3) ^ ((lane >> 3) & 3)) << 4);

    const unsigned char* gA0 = Aq + (size_t)(bm * 128 + r0) * GEMM_K + cswz;
    const unsigned char* gA1 = Aq + (size_t)(bm * 128 + r1) * GEMM_K + cswz;
    const unsigned char* gB0 = Bq + (size_t)(bn * 128 + r0) * GEMM_K + cswz;
    const unsigned char* gB1 = Bq + (size_t)(bn * 128 + r1) * GEMM_K + cswz;

    unsigned char* lA0 = &sA[(wave * 2 + 0) * 1024 + lane * 16];
    unsigned char* lA1 = &sA[(wave * 2 + 1) * 1024 + lane * 16];
    unsigned char* lB0 = &sB[(wave * 2 + 0) * 1024 + lane * 16];
    unsigned char* lB1 = &sB[(wave * 2 + 1) * 1024 + lane * 16];

    // ---- fragment addresses ----
    const int mloc = lane & 31;
    const int h    = lane >> 5;
    const int swz  = (mloc >> 1) & 3;            // (row>>1)&3, row-offsets are mult of 32
    const int wm   = wave >> 1, wn = wave & 1;

    unsigned alo[2], ahi[2], blo[2], bhi[2];
#pragma unroll
    for (int t = 0; t < 2; ++t) {
        const unsigned arow = (unsigned)(wm * 64 + t * 32 + mloc) << 6;
        const unsigned brow = (unsigned)(wn * 64 + t * 32 + mloc) << 6;
        alo[t] = arow + (((2 * h + 0) ^ swz) << 4);
        ahi[t] = arow + (((2 * h + 1) ^ swz) << 4);
        blo[t] = brow + (((2 * h + 0) ^ swz) << 4);
        bhi[t] = brow + (((2 * h + 1) ^ swz) << 4);
    }

    floatx16 acc[2][2];
#pragma unroll
    for (int i = 0; i < 2; ++i)
#pragma unroll
        for (int j = 0; j < 2; ++j)
            acc[i][j] = (floatx16)(0.0f);

    for (int kt = 0; kt < GEMM_K / 64; ++kt) {
        const int kb = kt * 64;
        __builtin_amdgcn_global_load_lds(
            (const __attribute__((address_space(1))) void*)(gA0 + kb),
            (__attribute__((address_space(3))) void*)lA0, 16, 0, 0);
        __builtin_amdgcn_global_load_lds(
            (const __attribute__((address_space(1))) void*)(gA1 + kb),
            (__attribute__((address_space(3))) void*)lA1, 16, 0, 0);
        __builtin_amdgcn_global_load_lds(
            (const __attribute__((address_space(1))) void*)(gB0 + kb),
            (__attribute__((address_space(3))) void*)lB0, 16, 0, 0);
        __builtin_amdgcn_global_load_lds(
            (const __attribute__((address_space(1))) void*)(gB1 + kb),
            (__attribute__((address_space(3))) void*)lB1, 16, 0, 0);
        __syncthreads();

        intx8 a[2], b[2];
#pragma unroll
        for (int t = 0; t < 2; ++t) {
            intx4 lo = *(const intx4*)&sA[alo[t]];
            intx4 hi = *(const intx4*)&sA[ahi[t]];
            a[t] = __builtin_shufflevector(lo, hi, 0, 1, 2, 3, 4, 5, 6, 7);
        }
#pragma unroll
        for (int t = 0; t < 2; ++t) {
            intx4 lo = *(const intx4*)&sB[blo[t]];
            intx4 hi = *(const intx4*)&sB[bhi[t]];
            b[t] = __builtin_shufflevector(lo, hi, 0, 1, 2, 3, 4, 5, 6, 7);
        }

#pragma unroll
        for (int i = 0; i < 2; ++i)
#pragma unroll
            for (int j = 0; j < 2; ++j)
                acc[i][j] = __builtin_amdgcn_mfma_scale_f32_32x32x64_f8f6f4(
                    a[i], b[j], acc[i][j],
                    0, 0,                    // cbsz = fp8(e4m3), blgp = fp8(e4m3)
                    0, 0x7f7f7f7f,           // opsel_a, scale_a = 1.0 (E8M0 127)
                    0, 0x7f7f7f7f);          // opsel_b, scale_b = 1.0

        __syncthreads();
    }

    // ---- epilogue: dequant + store ----
    const float inv = 1.0f / (sa[0] * sb[0]);
#pragma unroll
    for (int ti = 0; ti < 2; ++ti) {
        const int row0 = bm * 128 + wm * 64 + ti * 32 + 4 * h;
#pragma unroll
        for (int tj = 0; tj < 2; ++tj) {
            const int col = bn * 128 + wn * 64 + tj * 32 + mloc;
#pragma unroll
            for (int reg = 0; reg < 16; ++reg) {
                const int row = row0 + (reg & 3) + 8 * (reg >> 2);
                C[(size_t)row * GEMM_N + col] = acc[ti][tj][reg] * inv;
            }
        }
    }
}

extern "C" void kernel_launch(void* const* d_in, const int* in_sizes, int n_in,
                              void* d_out, int out_size, void* d_ws, size_t ws_size,
                              hipStream_t stream) {
    const float* x    = (const float*)d_in[0];   // [4,2048,2048]
    const float* w    = (const float*)d_in[1];   // [8192,2048]
    const float* s_in = (const float*)d_in[2];   // input_scale_e4m3
    const float* s_w  = (const float*)d_in[3];   // weight_scale_e4m3
    float* out = (float*)d_out;                  // [4,2048,8192] fp32

    unsigned char* qx = (unsigned char*)d_ws;                 // 16 MB
    unsigned char* qw = qx + (size_t)GEMM_M * GEMM_K;         // 16 MB

    const int nthr_x = in_sizes[0] / 16;
    const int nthr_w = in_sizes[1] / 16;
    quant_e4m3<<<nthr_x / 256, 256, 0, stream>>>(x, s_in, (int4*)qx);
    quant_e4m3<<<nthr_w / 256, 256, 0, stream>>>(w, s_w, (int4*)qw);

    dim3 grid(GEMM_N / 128, GEMM_M / 128);   // (64, 64)
    gemm_fp8_mx<<<grid, 256, 0, stream>>>(qx, qw, out, s_in, s_w);
}

// Round 3
// 484.591 us; speedup vs baseline: 1.3299x; 1.0008x over previous
//
#include <hip/hip_runtime.h>

typedef float floatx16 __attribute__((ext_vector_type(16)));
typedef int   intx4    __attribute__((ext_vector_type(4)));
typedef int   intx8    __attribute__((ext_vector_type(8)));

#define GEMM_M 8192   // A*B = 4*2048
#define GEMM_N 8192   // OUT
#define GEMM_K 2048   // C

// ---------------------------------------------------------------------------
// Quantize fp32 -> fp8 e4m3fn (OCP), scale applied before cast (RNE in HW).
// Fully coalesced: lane-contiguous float4 reads, lane-contiguous int writes.
// Each thread: 4 float4 at stride 256 -> 4 packed ints.
// ---------------------------------------------------------------------------
__global__ __launch_bounds__(256) void quant_e4m3(const float* __restrict__ x,
                                                  const float* __restrict__ scale,
                                                  int* __restrict__ q)
{
    const float s = scale[0];
    const int base = blockIdx.x * 1024 + threadIdx.x;
    const float4* __restrict__ x4 = (const float4*)x;
#pragma unroll
    for (int j = 0; j < 4; ++j) {
        float4 v = x4[base + j * 256];
        int p;
        p = __builtin_amdgcn_cvt_pk_fp8_f32(v.x * s, v.y * s, 0, false);
        p = __builtin_amdgcn_cvt_pk_fp8_f32(v.z * s, v.w * s, p, true);
        q[base + j * 256] = p;
    }
}

// ---------------------------------------------------------------------------
// TN fp8 GEMM via MX-scaled MFMA at unit scale (0x7f -> 2^0 = 1.0):
//   mfma_scale_f32_32x32x64_f8f6f4, cbsz=blgp=0 (fp8 e4m3 both operands).
//
// 128(M) x 256(N) block tile, BK=64, 256 threads (4 waves, 2x2), wave tile
// 64x128 = 2x4 grid of 32x32 tiles -> 8 MFMA from 2 A-frags + 4 B-frags
// (0.75 b128-pair reads per MFMA vs 1.0 at 64x64 wave tiles).
//
// LDS staged flat via global_load_lds width=16. 16B chunks XOR-swizzled on
// the GLOBAL side with s(r) = (r>>1)&3: LDS chunk c of row r holds global
// chunk c ^ s(r). b128 fragment reads hit all 32 banks exactly 4x per
// half-wave phase (the b128 minimum).
//
// A-frag (32x32x64): lane holds A[m=lane&31][k=32*(lane>>5)+j], j=0..31,
// i.e. swizzled chunks {2h^swz, (2h+1)^swz} of its row (h=lane>>5).
// C/D: col=lane&31, row=(reg&3)+8*(reg>>2)+4*(lane>>5)  [m74/m101]
// ---------------------------------------------------------------------------
__global__ __launch_bounds__(256, 2) void gemm_fp8_mx(
    const unsigned char* __restrict__ Aq,   // [M,K] fp8
    const unsigned char* __restrict__ Bq,   // [N,K] fp8
    float* __restrict__ C,                  // [M,N]
    const float* __restrict__ sa,
    const float* __restrict__ sb)
{
    __shared__ __align__(16) unsigned char sA[128 * 64];   //  8 KB
    __shared__ __align__(16) unsigned char sB[256 * 64];   // 16 KB

    const int tid  = threadIdx.x;
    const int lane = tid & 63;
    const int wave = tid >> 6;
    const int bn   = blockIdx.x;   // N block (256 wide)
    const int bm   = blockIdx.y;   // M block (128 tall)

    // ---- staging: segs of 1024B (16 rows x 64B). A: 8 segs, B: 16 segs.
    // Wave w: A segs {2w,2w+1}, B segs {4w..4w+3}.
    // seg s, lane l -> LDS offset s*1024 + l*16 ; tile row r = s*16 + (l>>2)
    // global chunk = (l&3) ^ ((r>>1)&3) = (l&3) ^ ((l>>3)&3)
    const int rseg = lane >> 2;
    const int cswz = (((lane & 3) ^ ((lane >> 3) & 3)) << 4);

    const unsigned char* gA[2];
    unsigned char*       lA[2];
#pragma unroll
    for (int t = 0; t < 2; ++t) {
        const int s = wave * 2 + t;
        gA[t] = Aq + (size_t)(bm * 128 + s * 16 + rseg) * GEMM_K + cswz;
        lA[t] = &sA[s * 1024 + lane * 16];
    }
    const unsigned char* gB[4];
    unsigned char*       lB[4];
#pragma unroll
    for (int t = 0; t < 4; ++t) {
        const int s = wave * 4 + t;
        gB[t] = Bq + (size_t)(bn * 256 + s * 16 + rseg) * GEMM_K + cswz;
        lB[t] = &sB[s * 1024 + lane * 16];
    }

    // ---- fragment addresses ----
    const int mloc = lane & 31;
    const int h    = lane >> 5;
    const int swz  = (mloc >> 1) & 3;   // row-offsets below are multiples of 32
    const int wm   = wave >> 1, wn = wave & 1;

    unsigned alo[2], ahi[2];
#pragma unroll
    for (int t = 0; t < 2; ++t) {
        const unsigned row = (unsigned)(wm * 64 + t * 32 + mloc) << 6;
        alo[t] = row + (((2 * h + 0) ^ swz) << 4);
        ahi[t] = row + (((2 * h + 1) ^ swz) << 4);
    }
    unsigned blo[4], bhi[4];
#pragma unroll
    for (int t = 0; t < 4; ++t) {
        const unsigned row = (unsigned)(wn * 128 + t * 32 + mloc) << 6;
        blo[t] = row + (((2 * h + 0) ^ swz) << 4);
        bhi[t] = row + (((2 * h + 1) ^ swz) << 4);
    }

    floatx16 acc[2][4];
#pragma unroll
    for (int i = 0; i < 2; ++i)
#pragma unroll
        for (int j = 0; j < 4; ++j)
            acc[i][j] = (floatx16)(0.0f);

    for (int kt = 0; kt < GEMM_K / 64; ++kt) {
        const int kb = kt * 64;
#pragma unroll
        for (int t = 0; t < 2; ++t)
            __builtin_amdgcn_global_load_lds(
                (const __attribute__((address_space(1))) void*)(gA[t] + kb),
                (__attribute__((address_space(3))) void*)lA[t], 16, 0, 0);
#pragma unroll
        for (int t = 0; t < 4; ++t)
            __builtin_amdgcn_global_load_lds(
                (const __attribute__((address_space(1))) void*)(gB[t] + kb),
                (__attribute__((address_space(3))) void*)lB[t], 16, 0, 0);
        __syncthreads();

        intx8 a[2], b[4];
#pragma unroll
        for (int t = 0; t < 2; ++t) {
            intx4 lo = *(const intx4*)&sA[alo[t]];
            intx4 hi = *(const intx4*)&sA[ahi[t]];
            a[t] = __builtin_shufflevector(lo, hi, 0, 1, 2, 3, 4, 5, 6, 7);
        }
#pragma unroll
        for (int t = 0; t < 4; ++t) {
            intx4 lo = *(const intx4*)&sB[blo[t]];
            intx4 hi = *(const intx4*)&sB[bhi[t]];
            b[t] = __builtin_shufflevector(lo, hi, 0, 1, 2, 3, 4, 5, 6, 7);
        }

#pragma unroll
        for (int i = 0; i < 2; ++i)
#pragma unroll
            for (int j = 0; j < 4; ++j)
                acc[i][j] = __builtin_amdgcn_mfma_scale_f32_32x32x64_f8f6f4(
                    a[i], b[j], acc[i][j],
                    0, 0,                    // cbsz = fp8(e4m3), blgp = fp8(e4m3)
                    0, 0x7f7f7f7f,           // opsel_a, scale_a = 1.0 (E8M0 127)
                    0, 0x7f7f7f7f);          // opsel_b, scale_b = 1.0

        __syncthreads();
    }

    // ---- epilogue: dequant + store ----
    const float inv = 1.0f / (sa[0] * sb[0]);
#pragma unroll
    for (int ti = 0; ti < 2; ++ti) {
        const int row0 = bm * 128 + wm * 64 + ti * 32 + 4 * h;
#pragma unroll
        for (int tj = 0; tj < 4; ++tj) {
            const int col = bn * 256 + wn * 128 + tj * 32 + mloc;
#pragma unroll
            for (int reg = 0; reg < 16; ++reg) {
                const int row = row0 + (reg & 3) + 8 * (reg >> 2);
                C[(size_t)row * GEMM_N + col] = acc[ti][tj][reg] * inv;
            }
        }
    }
}

extern "C" void kernel_launch(void* const* d_in, const int* in_sizes, int n_in,
                              void* d_out, int out_size, void* d_ws, size_t ws_size,
                              hipStream_t stream) {
    const float* x    = (const float*)d_in[0];   // [4,2048,2048]
    const float* w    = (const float*)d_in[1];   // [8192,2048]
    const float* s_in = (const float*)d_in[2];   // input_scale_e4m3
    const float* s_w  = (const float*)d_in[3];   // weight_scale_e4m3
    float* out = (float*)d_out;                  // [4,2048,8192] fp32

    unsigned char* qx = (unsigned char*)d_ws;                 // 16 MB
    unsigned char* qw = qx + (size_t)GEMM_M * GEMM_K;         // 16 MB

    // 16 elems/thread, 1024 elems/block
    quant_e4m3<<<in_sizes[0] / 4096, 256, 0, stream>>>(x, s_in, (int*)qx);
    quant_e4m3<<<in_sizes[1] / 4096, 256, 0, stream>>>(w, s_w, (int*)qw);

    dim3 grid(GEMM_N / 256, GEMM_M / 128);   // (32, 64)
    gemm_fp8_mx<<<grid, 256, 0, stream>>>(qx, qw, out, s_in, s_w);
}